// Round 12
// baseline (5866.558 us; speedup 1.0000x reference)
//
#include <hip/hip_runtime.h>
#include <math.h>
#include <float.h>

#define BNS_C 0.9999950000374996f /* 1/sqrt(1+1e-5) */

typedef __bf16 bf8 __attribute__((ext_vector_type(8)));
typedef float f4 __attribute__((ext_vector_type(4)));
union I4BF8 { int4 i; bf8 b; };

static __device__ __forceinline__ unsigned short f2bf(float f) {
    unsigned u = __float_as_uint(f);
    u += 0x7fff + ((u >> 16) & 1);          // round-to-nearest-even
    return (unsigned short)(u >> 16);
}

// wave top-20 select (value desc, index asc tie-break). Each lane holds up to 2
// candidates (v0,i0),(v1,i1). Winners go to cvr/cir[0..19] (lane0) or outg.
// Returns the 20th (last) selected value.
static __device__ __forceinline__ float sel20(float v0, int i0, float v1, int i1,
                                              float* cvr, unsigned short* cir,
                                              int* outg, int lane) {
    float last = -FLT_MAX;
    for (int it = 0; it < 20; ++it) {
        bool s1 = (v1 > v0) || (v1 == v0 && i1 < i0);
        float bv = s1 ? v1 : v0; int bm = s1 ? i1 : i0; int bc = s1 ? lane + 64 : lane;
        for (int off = 32; off; off >>= 1) {
            float ov = __shfl_down(bv, off); int om = __shfl_down(bm, off); int oc = __shfl_down(bc, off);
            if (ov > bv || (ov == bv && om < bm)) { bv = ov; bm = om; bc = oc; }
        }
        bv = __shfl(bv, 0); bm = __shfl(bm, 0); bc = __shfl(bc, 0);
        if (lane == 0) {
            if (outg) outg[it] = bm;
            else { cvr[it] = bv; cir[it] = (unsigned short)bm; }
        }
        if (bc == lane) v0 = -FLT_MAX;
        else if (bc == lane + 64) v1 = -FLT_MAX;
        last = bv;
    }
    return last;
}

// ------- x[b][6][1024] -> X0[b][n][8] (zero-padded) + xx norms -------
__global__ void k_xin_t(const float* __restrict__ x, float* __restrict__ X0, float* __restrict__ xx) {
    int i = blockIdx.x * 256 + threadIdx.x;   // over 16384 points
    int b = i >> 10, n = i & 1023;
    const float* xb = x + (((size_t)b * 6) << 10) + n;
    float4* o4 = (float4*)(X0 + ((size_t)i << 3));
    float v0 = xb[0], v1 = xb[1 << 10], v2 = xb[2 << 10];
    float v3 = xb[3 << 10], v4 = xb[4 << 10], v5 = xb[5 << 10];
    o4[0] = make_float4(v0, v1, v2, v3);
    o4[1] = make_float4(v4, v5, 0.f, 0.f);
    xx[i] = v0*v0 + v1*v1 + v2*v2 + v3*v3 + v4*v4 + v5*v5;
}

// ------- fused KNN: Gram tile + streaming top-20, D never touches HBM -------
// block = (n-tile of 32 rows, batch). Scores v[m] = 2*X[n]·X[m] - xx[m]
// (the -xx[n] term is row-constant and drops out of selection).
__global__ __launch_bounds__(256) void k_knn(const float* __restrict__ X, const float* __restrict__ xx,
                                             int* __restrict__ idxo, int Cp, int cpsh, int chsh) {
    extern __shared__ float smem[];
    float* Af  = smem;                       // [Cp][34]   A strip, c-major
    float* Bf  = Af + (size_t)Cp * 34;       // [32][68]   B c-chunk
    float* Dt  = Bf + 2176;                  // [32][68]   score tile
    float* cv  = Dt + 2176;                  // [32][112]  candidate values (88 + 20 temp + pad)
    float* xxs = cv + 3584;                  // [64]
    float* thr = xxs + 64;                   // [32]
    int*   cnt = (int*)(thr + 32);           // [32]
    unsigned short* ci = (unsigned short*)(cnt + 32);  // [32][112] candidate indices

    int b = blockIdx.y, n0 = blockIdx.x << 5;
    int tid = threadIdx.x;
    int lane = tid & 63, wv = tid >> 6;
    int ti = tid & 15, tj = tid >> 4;
    const float* Xb = X + ((((size_t)b) << 10)) * Cp;

    // A strip: rows n0..n0+31, stored c-major Af[c][row]
    for (int e = tid; e < (Cp << 5); e += 256) {
        int c = e & (Cp - 1), row = e >> cpsh;
        Af[c * 34 + row] = Xb[(size_t)(n0 + row) * Cp + c];
    }
    int ch = 1 << chsh;

    for (int mt = 0; mt < 16; ++mt) {
        int m0 = mt << 6;
        float acc[2][4] = {};
        for (int c0 = 0; c0 < Cp; c0 += 32) {
            __syncthreads();   // prior compute/selection done -> safe to overwrite Bf/Dt
            if (c0 == 0 && tid < 64) xxs[tid] = xx[(b << 10) + m0 + tid];
            for (int e = tid; e < (ch << 6); e += 256) {
                int cc = e & (ch - 1), row = e >> chsh;
                Bf[cc * 68 + row] = Xb[(size_t)(m0 + row) * Cp + c0 + cc];
            }
            __syncthreads();
#pragma unroll 4
            for (int c = 0; c < ch; ++c) {
                const float2 av = *(const float2*)(Af + (c0 + c) * 34 + 2 * tj);
                const float4 bv = *(const float4*)(Bf + c * 68 + 4 * ti);
                acc[0][0] += av.x * bv.x; acc[0][1] += av.x * bv.y;
                acc[0][2] += av.x * bv.z; acc[0][3] += av.x * bv.w;
                acc[1][0] += av.y * bv.x; acc[1][1] += av.y * bv.y;
                acc[1][2] += av.y * bv.z; acc[1][3] += av.y * bv.w;
            }
        }
        {
            const float4 xm = *(const float4*)(xxs + 4 * ti);
#pragma unroll
            for (int a = 0; a < 2; ++a) {
                float4 o;
                o.x = 2.f * acc[a][0] - xm.x; o.y = 2.f * acc[a][1] - xm.y;
                o.z = 2.f * acc[a][2] - xm.z; o.w = 2.f * acc[a][3] - xm.w;
                *(float4*)(Dt + (2 * tj + a) * 68 + 4 * ti) = o;
            }
        }
        __syncthreads();
        // selection: wave wv owns rows wv*8 .. wv*8+7 (all state wave-private)
        for (int rr = 0; rr < 8; ++rr) {
            int r = (wv << 3) + rr;
            float v = Dt[r * 68 + lane];
            int m = m0 + lane;
            float* cvr = cv + r * 112;
            unsigned short* cir = ci + r * 112;
            if (mt == 0) {
                float last = sel20(v, m, -FLT_MAX, 2048, cvr, cir, nullptr, lane);
                if (lane == 0) { cnt[r] = 20; thr[r] = last; }
            } else {
                float tr = thr[r];
                unsigned long long mask = __ballot(v >= tr);
                if (mask) {
                    int cn = cnt[r];
                    if (cn > 24) {      // compact: exact top-20 of candidates -> slots 0..19
                        float v0 = (lane < cn) ? cvr[lane] : -FLT_MAX;
                        int   i0 = (lane < cn) ? (int)cir[lane] : 2048;
                        float v1 = (lane + 64 < cn) ? cvr[lane + 64] : -FLT_MAX;
                        int   i1 = (lane + 64 < cn) ? (int)cir[lane + 64] : 2048;
                        float last = sel20(v0, i0, v1, i1, cvr + 88, cir + 88, nullptr, lane);
                        if (lane < 20) { cvr[lane] = cvr[88 + lane]; cir[lane] = cir[88 + lane]; }
                        if (lane == 0) { cnt[r] = 20; thr[r] = last; }
                        tr = last; cn = 20;
                        mask = __ballot(v >= tr);
                    }
                    if (mask) {         // append beaters (cn<=24 -> max fill 88, cap safe)
                        int pre = __popcll(mask & ((1ULL << lane) - 1));
                        if (v >= tr) { cvr[cn + pre] = v; cir[cn + pre] = (unsigned short)m; }
                        if (lane == 0) cnt[r] = cn + __popcll(mask);
                    }
                }
            }
        }
    }
    // final exact top-20 (same comparator as jax.lax.top_k) from candidate superset
    for (int rr = 0; rr < 8; ++rr) {
        int r = (wv << 3) + rr;
        int cn = cnt[r];
        float* cvr = cv + r * 112;
        unsigned short* cir = ci + r * 112;
        float v0 = (lane < cn) ? cvr[lane] : -FLT_MAX;
        int   i0 = (lane < cn) ? (int)cir[lane] : 2048;
        float v1 = (lane + 64 < cn) ? cvr[lane + 64] : -FLT_MAX;
        int   i1 = (lane + 64 < cn) ? (int)cir[lane + 64] : 2048;
        sel20(v0, i0, v1, i1, nullptr, nullptr, idxo + (size_t)((b << 10) + n0 + r) * 20, lane);
    }
}

// ---- V[b][n][o] = X·Wa^T, U[b][n][o] = X·(Wb-Wa)^T ; w is [O][2C] ----
__global__ __launch_bounds__(256) void k_uv(const float* __restrict__ X, const float* __restrict__ w,
                                            float* __restrict__ V, float* __restrict__ U,
                                            int Cp, int C, int O) {
    int n0 = blockIdx.x * 64, o0 = blockIdx.y * 64, b = blockIdx.z;
    __shared__ float Xs[64][33], Was[64][33], Wds[64][33];
    int tid = threadIdx.x, ti = tid & 15, tj = tid >> 4;
    float accv[4][4] = {}, accu[4][4] = {};
    const float* Xb = X + (((size_t)b) << 10) * Cp;
    int W2 = 2 * C;
    for (int c0 = 0; c0 < Cp; c0 += 32) {
        for (int e = tid; e < 2048; e += 256) {
            int row = e >> 5, cc = e & 31, c = c0 + cc;
            Xs[row][cc] = (c < Cp) ? Xb[(size_t)(n0 + row) * Cp + c] : 0.f;
            float wa = 0.f, wd = 0.f;
            if (c < C) {
                float a_ = w[(size_t)(o0 + row) * W2 + c];
                float b_ = w[(size_t)(o0 + row) * W2 + C + c];
                wa = a_; wd = b_ - a_;
            }
            Was[row][cc] = wa; Wds[row][cc] = wd;
        }
        __syncthreads();
#pragma unroll 8
        for (int cc = 0; cc < 32; ++cc) {
            float xv[4], av[4], dv[4];
#pragma unroll
            for (int a = 0; a < 4; ++a) xv[a] = Xs[tj + 16 * a][cc];
#pragma unroll
            for (int q = 0; q < 4; ++q) { av[q] = Was[ti + 16 * q][cc]; dv[q] = Wds[ti + 16 * q][cc]; }
#pragma unroll
            for (int a = 0; a < 4; ++a)
#pragma unroll
                for (int q = 0; q < 4; ++q) { accv[a][q] += xv[a] * av[q]; accu[a][q] += xv[a] * dv[q]; }
        }
        __syncthreads();
    }
#pragma unroll
    for (int a = 0; a < 4; ++a) {
        int n = n0 + tj + 16 * a;
#pragma unroll
        for (int q = 0; q < 4; ++q) {
            int o = o0 + ti + 16 * q;
            size_t oi = ((size_t)((b << 10) + n)) * O + o;
            V[oi] = accv[a][q]; U[oi] = accu[a][q];
        }
    }
}

// ---- out[b][n][o] = max_k leaky(bn(V[m_k]+U[n])); writes f32 Xo, k-sliced bf16 HB, xx ----
__global__ __launch_bounds__(256) void k_gmax(const float* __restrict__ V, const float* __restrict__ U,
                                              const int* __restrict__ idx,
                                              const float* __restrict__ gg, const float* __restrict__ bb,
                                              float* __restrict__ Xo, float* __restrict__ xx,
                                              unsigned short* __restrict__ HB, int coff, int O) {
    __shared__ float sxx[4];
    int tid = threadIdx.x;
    int Tn = 256 / O;
    int j = tid / O, o = tid - j * O;
    int pt = blockIdx.x * Tn + j;          // global point = b*1024+n
    int b = pt >> 10, n = pt & 1023;
    float uv = U[(size_t)pt * O + o];
    float gv = gg[o], bv = bb[o];
    const int* ip = idx + (size_t)pt * 20;
    float mx = -FLT_MAX;
    for (int k = 0; k < 20; ++k) {
        int m = ip[k] & 1023;
        float vv = V[(size_t)((b << 10) + m) * O + o];
        float y = gv * ((vv + uv) * BNS_C) + bv;
        y = y > 0.f ? y : 0.2f * y;
        mx = fmaxf(mx, y);
    }
    Xo[(size_t)pt * O + o] = mx;
    int c = coff + o;
    HB[(((size_t)(b * 16 + (c >> 5)) << 10) + n) * 32 + (c & 31)] = f2bf(mx);
    float s = mx * mx;
#pragma unroll
    for (int off = 32; off; off >>= 1) s += __shfl_down(s, off);
    int wid = tid >> 6, lane = tid & 63;
    if (lane == 0) sxx[wid] = s;
    __syncthreads();
    if (o == 0) {
        int Wpp = O >> 6;
        float t = 0.f;
        for (int w = 0; w < Wpp; ++w) t += sxx[j * Wpp + w];
        xx[pt] = t;
    }
}

// ------- fused MFMA GEMM + BN/leaky + partial max/sum pool over a 256-row n-tile -------
__global__ __launch_bounds__(256) void k_final_mfma(const unsigned short* __restrict__ HB,
                                                    const float* __restrict__ w5,
                                                    const float* __restrict__ g5,
                                                    const float* __restrict__ b5,
                                                    float* __restrict__ pp) {
    int b = blockIdx.x;
    int nt = blockIdx.z;
    int wv = threadIdx.x >> 6, lane = threadIdx.x & 63;
    int r = lane & 15, q = lane >> 4;
    int o = blockIdx.y * 64 + wv * 16 + r;
    bf8 Bfr[16];
    const float* wrow = w5 + (size_t)o * 512 + q * 8;
#pragma unroll
    for (int s = 0; s < 16; ++s) {
        float4 f0 = *(const float4*)(wrow + s * 32);
        float4 f1 = *(const float4*)(wrow + s * 32 + 4);
        I4BF8 u_;
        u_.i.x = f2bf(f0.x) | ((unsigned)f2bf(f0.y) << 16);
        u_.i.y = f2bf(f0.z) | ((unsigned)f2bf(f0.w) << 16);
        u_.i.z = f2bf(f1.x) | ((unsigned)f2bf(f1.y) << 16);
        u_.i.w = f2bf(f1.z) | ((unsigned)f2bf(f1.w) << 16);
        Bfr[s] = u_.b;
    }
    float gb = g5[o] * BNS_C, bv = b5[o];
    float mx = -FLT_MAX, sm = 0.f;
    for (int g = 0; g < 4; ++g) {
        int row0 = (nt << 8) + (g << 6);
        f4 C0 = {0.f, 0.f, 0.f, 0.f}, C1 = C0, C2 = C0, C3 = C0;
#pragma unroll
        for (int s = 0; s < 16; ++s) {
            const unsigned short* slab = HB + (((size_t)(b * 16 + s) << 10) + row0) * 32 + q * 8;
            I4BF8 A0, A1, A2, A3;
            A0.i = *(const int4*)(slab + (size_t)( 0 + r) * 32);
            A1.i = *(const int4*)(slab + (size_t)(16 + r) * 32);
            A2.i = *(const int4*)(slab + (size_t)(32 + r) * 32);
            A3.i = *(const int4*)(slab + (size_t)(48 + r) * 32);
            C0 = __builtin_amdgcn_mfma_f32_16x16x32_bf16(A0.b, Bfr[s], C0, 0, 0, 0);
            C1 = __builtin_amdgcn_mfma_f32_16x16x32_bf16(A1.b, Bfr[s], C1, 0, 0, 0);
            C2 = __builtin_amdgcn_mfma_f32_16x16x32_bf16(A2.b, Bfr[s], C2, 0, 0, 0);
            C3 = __builtin_amdgcn_mfma_f32_16x16x32_bf16(A3.b, Bfr[s], C3, 0, 0, 0);
        }
#pragma unroll
        for (int e = 0; e < 4; ++e) {
            float y0 = gb * C0[e] + bv; y0 = y0 > 0.f ? y0 : 0.2f * y0; mx = fmaxf(mx, y0); sm += y0;
            float y1 = gb * C1[e] + bv; y1 = y1 > 0.f ? y1 : 0.2f * y1; mx = fmaxf(mx, y1); sm += y1;
            float y2 = gb * C2[e] + bv; y2 = y2 > 0.f ? y2 : 0.2f * y2; mx = fmaxf(mx, y2); sm += y2;
            float y3 = gb * C3[e] + bv; y3 = y3 > 0.f ? y3 : 0.2f * y3; mx = fmaxf(mx, y3); sm += y3;
        }
    }
    mx = fmaxf(mx, __shfl_down(mx, 32)); sm += __shfl_down(sm, 32);
    mx = fmaxf(mx, __shfl_down(mx, 16)); sm += __shfl_down(sm, 16);
    if (q == 0) {
        float* pb = pp + (size_t)(nt * 16 + b) * 2048;
        pb[o] = mx;
        pb[1024 + o] = sm;
    }
}

// ---- wl1 FC fused with the n-tile partial reduction: reads pp directly ----
__global__ __launch_bounds__(256) void k_fc2p(const float* __restrict__ pp, const float* __restrict__ w,
                                              const float* __restrict__ gg, const float* __restrict__ bb,
                                              float* __restrict__ out, int O) {
    int gw = blockIdx.x * 4 + (threadIdx.x >> 6);
    int lane = threadIdx.x & 63;
    int r = gw / O, o = gw - r * O;
    const float* wr = w + (size_t)o * 2048;
    float s = 0.f;
    for (int c = lane; c < 2048; c += 64) {
        const float* q0 = pp + (size_t)r * 2048 + c;
        float v;
        if (c < 1024) {
            v = fmaxf(fmaxf(q0[0], q0[16 * 2048]), fmaxf(q0[32 * 2048], q0[48 * 2048]));
        } else {
            v = (q0[0] + q0[16 * 2048] + q0[32 * 2048] + q0[48 * 2048]) * (1.f / 1024.f);
        }
        s += v * wr[c];
    }
#pragma unroll
    for (int off = 32; off; off >>= 1) s += __shfl_down(s, off);
    if (lane == 0) {
        float y = gg[o] * (s * BNS_C) + bb[o];
        out[gw] = y > 0.f ? y : 0.2f * y;
    }
}

// ------- FC tail mega-kernel -------
__global__ __launch_bounds__(256) void k_fc_tail(const float* __restrict__ z1,
                                                 const float* __restrict__ wl2, const float* __restrict__ g7, const float* __restrict__ b7,
                                                 const float* __restrict__ wl21,
                                                 const float* __restrict__ wl22, const float* __restrict__ g8, const float* __restrict__ b8,
                                                 const float* __restrict__ wl3,
                                                 float* __restrict__ out) {
    __shared__ float L0[4096];
    __shared__ float L1[2048];
    __shared__ float L2[1024];
    __shared__ float L3[512];
    int tid = threadIdx.x;
    for (int i = tid; i < 4096; i += 256) L0[i] = z1[i];
    __syncthreads();
    for (int idx = tid; idx < 2048; idx += 256) {
        int r = idx >> 7, o = idx & 127;
        const float* wr = wl2 + (size_t)o * 256;
        const float* ir = L0 + r * 256;
        float s = 0.f;
        for (int c = 0; c < 256; ++c) s += ir[c] * wr[c];
        float y = g7[o] * (s * BNS_C) + b7[o];
        L1[r * 128 + o] = y > 0.f ? y : 0.2f * y;
    }
    __syncthreads();
    for (int idx = tid; idx < 1024; idx += 256) {
        int r = idx >> 6, o = idx & 63;
        const float* wr = wl21 + (size_t)o * 128;
        const float* ir = L1 + r * 128;
        float s = 0.f;
        for (int c = 0; c < 128; ++c) s += ir[c] * wr[c];
        L2[r * 64 + o] = s;
    }
    __syncthreads();
    for (int idx = tid; idx < 512; idx += 256) {
        int r = idx >> 5, o = idx & 31;
        const float* wr = wl22 + (size_t)o * 64;
        const float* ir = L2 + r * 64;
        float s = 0.f;
        for (int c = 0; c < 64; ++c) s += ir[c] * wr[c];
        float y = g8[o] * (s * BNS_C) + b8[o];
        L3[r * 32 + o] = 0.5f * y * (1.f + erff(y * 0.70710678118654752f));
    }
    __syncthreads();
    for (int idx = tid; idx < 1440; idx += 256) {
        int r = idx / 90, o = idx - r * 90;
        const float* wr = wl3 + (size_t)o * 32;
        const float* ir = L3 + r * 32;
        float s = 0.f;
        for (int c = 0; c < 32; ++c) s += ir[c] * wr[c];
        out[r * 90 + o] = s;
    }
}

extern "C" void kernel_launch(void* const* d_in, const int* in_sizes, int n_in,
                              void* d_out, int out_size, void* d_ws, size_t ws_size,
                              hipStream_t stream) {
    typedef const float* fp;
    fp x  = (fp)d_in[0];
    fp w1 = (fp)d_in[2],  g1 = (fp)d_in[3],  b1 = (fp)d_in[4];
    fp w2 = (fp)d_in[5],  g2 = (fp)d_in[6],  b2 = (fp)d_in[7];
    fp w3 = (fp)d_in[8],  g3 = (fp)d_in[9],  b3 = (fp)d_in[10];
    fp w4 = (fp)d_in[11], g4 = (fp)d_in[12], b4 = (fp)d_in[13];
    fp w5 = (fp)d_in[14], g5 = (fp)d_in[15], b5 = (fp)d_in[16];
    fp wl1 = (fp)d_in[17], g6 = (fp)d_in[18], b6 = (fp)d_in[19];
    fp wl2 = (fp)d_in[20], g7 = (fp)d_in[21], b7 = (fp)d_in[22];
    fp wl21 = (fp)d_in[23], wl22 = (fp)d_in[24];
    fp g8 = (fp)d_in[25], b8 = (fp)d_in[26], wl3 = (fp)d_in[27];

    char* ws = (char*)d_ws;
    size_t off = 0;
    auto alloc = [&](size_t floats) { float* p_ = (float*)(ws + off); off += floats * 4; off = (off + 255) & ~(size_t)255; return p_; };
    float* X0  = alloc(131072);       // 16*1024*8
    float* X1  = alloc(1048576);      // [b][n][64]
    float* X2  = alloc(1048576);
    float* X3  = alloc(2097152);      // [b][n][128]
    float* X4  = alloc(4194304);      // [b][n][256]
    float* xx  = alloc(16384);
    int*   nbr = (int*)alloc(327680); // 16*1024*20
    unsigned short* HB = (unsigned short*)alloc(4194304);  // bf16 k-sliced [b][s][n][32]
    float* pp  = alloc(131072);       // 4 n-tile partials x 16 b x 2048
    float* z1  = alloc(4096);
    float* pool = alloc(8388608);     // V+U only (D eliminated)
    float* V = pool;
    float* U = pool + 4194304;

    k_xin_t<<<64, 256, 0, stream>>>(x, X0, xx);

    struct Blk { const float* Xin; int Cp, C, O, coff, cpsh, chsh; const float *w, *g, *b; float* Xout; };
    Blk blks[4] = {
        {X0, 8,   6,   64,  0,   3, 3, w1, g1, b1, X1},
        {X1, 64,  64,  64,  64,  6, 5, w2, g2, b2, X2},
        {X2, 64,  64,  128, 128, 6, 5, w3, g3, b3, X3},
        {X3, 128, 128, 256, 256, 7, 5, w4, g4, b4, X4},
    };
    for (int i = 0; i < 4; ++i) {
        const Blk& B_ = blks[i];
        size_t lds = ((size_t)B_.Cp * 34 + 8032) * 4 + 7296;
        k_knn<<<dim3(32, 16), 256, lds, stream>>>(B_.Xin, xx, nbr, B_.Cp, B_.cpsh, B_.chsh);
        k_uv<<<dim3(16, B_.O / 64, 16), 256, 0, stream>>>(B_.Xin, B_.w, V, U, B_.Cp, B_.C, B_.O);
        int Tn = 256 / B_.O;
        k_gmax<<<16384 / Tn, 256, 0, stream>>>(V, U, nbr, B_.g, B_.b, B_.Xout, xx, HB, B_.coff, B_.O);
    }

    k_final_mfma<<<dim3(16, 16, 4), 256, 0, stream>>>(HB, w5, g5, b5, pp);

    k_fc2p<<<(16 * 256) / 4, 256, 0, stream>>>(pp, wl1, g6, b6, z1, 256);
    k_fc_tail<<<1, 256, 0, stream>>>(z1, wl2, g7, b7, wl21, wl22, g8, b8, wl3, (float*)d_out);
}

// Round 13
// 958.755 us; speedup vs baseline: 6.1189x; 6.1189x over previous
//
#include <hip/hip_runtime.h>
#include <math.h>
#include <float.h>

#define BNS_C 0.9999950000374996f /* 1/sqrt(1+1e-5) */

typedef __bf16 bf8 __attribute__((ext_vector_type(8)));
typedef float f4 __attribute__((ext_vector_type(4)));
union I4BF8 { int4 i; bf8 b; };

static __device__ __forceinline__ unsigned short f2bf(float f) {
    unsigned u = __float_as_uint(f);
    u += 0x7fff + ((u >> 16) & 1);          // round-to-nearest-even
    return (unsigned short)(u >> 16);
}

// ------- x[b][6][1024] -> X0[b][n][8] (zero-padded) + xx norms -------
__global__ void k_xin_t(const float* __restrict__ x, float* __restrict__ X0, float* __restrict__ xx) {
    int i = blockIdx.x * 256 + threadIdx.x;   // over 16384 points
    int b = i >> 10, n = i & 1023;
    const float* xb = x + (((size_t)b * 6) << 10) + n;
    float4* o4 = (float4*)(X0 + ((size_t)i << 3));
    float v0 = xb[0], v1 = xb[1 << 10], v2 = xb[2 << 10];
    float v3 = xb[3 << 10], v4 = xb[4 << 10], v5 = xb[5 << 10];
    o4[0] = make_float4(v0, v1, v2, v3);
    o4[1] = make_float4(v4, v5, 0.f, 0.f);
    xx[i] = v0*v0 + v1*v1 + v2*v2 + v3*v3 + v4*v4 + v5*v5;
}

// ---- D[z][n][m] = 2*X[n]·X[m] - xx[n] - xx[m]; c-major LDS, b128 frags ----
// thread (ti,tj): rows n0+4tj..+3, cols m0+4ti..+3. Stride 68 floats = 272 B (16B-aligned).
__global__ __launch_bounds__(256) void k_gram2(const float* __restrict__ X, const float* __restrict__ xx,
                                               float* __restrict__ D, int Cp, int b0) {
    int z = blockIdx.z, b = b0 + z;
    int n0 = blockIdx.y * 64, m0 = blockIdx.x * 64;
    __shared__ float As[32 * 68], Bs[32 * 68];   // [cc][row]
    int tid = threadIdx.x;
    int ti = tid & 15, tj = tid >> 4;
    float acc[4][4] = {};
    const float* Xb = X + (((size_t)b) << 10) * Cp;
    for (int c0 = 0; c0 < Cp; c0 += 32) {
        for (int e = tid; e < 2048; e += 256) {
            int row = e >> 5, cc = e & 31, c = c0 + cc;
            float a = 0.f, bb = 0.f;
            if (c < Cp) {
                a  = Xb[(size_t)(n0 + row) * Cp + c];
                bb = Xb[(size_t)(m0 + row) * Cp + c];
            }
            As[cc * 68 + row] = a; Bs[cc * 68 + row] = bb;
        }
        __syncthreads();
#pragma unroll 8
        for (int cc = 0; cc < 32; ++cc) {
            const float4 av = *(const float4*)(As + cc * 68 + 4 * tj);
            const float4 bv = *(const float4*)(Bs + cc * 68 + 4 * ti);
            acc[0][0] += av.x * bv.x; acc[0][1] += av.x * bv.y; acc[0][2] += av.x * bv.z; acc[0][3] += av.x * bv.w;
            acc[1][0] += av.y * bv.x; acc[1][1] += av.y * bv.y; acc[1][2] += av.y * bv.z; acc[1][3] += av.y * bv.w;
            acc[2][0] += av.z * bv.x; acc[2][1] += av.z * bv.y; acc[2][2] += av.z * bv.z; acc[2][3] += av.z * bv.w;
            acc[3][0] += av.w * bv.x; acc[3][1] += av.w * bv.y; acc[3][2] += av.w * bv.z; acc[3][3] += av.w * bv.w;
        }
        __syncthreads();
    }
    const float4 xm = *(const float4*)(xx + (b << 10) + m0 + 4 * ti);
#pragma unroll
    for (int a = 0; a < 4; ++a) {
        int n = n0 + 4 * tj + a;
        float xn = xx[(b << 10) + n];
        float4 o;
        o.x = 2.f * acc[a][0] - xn - xm.x;
        o.y = 2.f * acc[a][1] - xn - xm.y;
        o.z = 2.f * acc[a][2] - xn - xm.z;
        o.w = 2.f * acc[a][3] - xn - xm.w;
        *(float4*)(D + ((size_t)((z << 10) + n) << 10) + m0 + 4 * ti) = o;
    }
}

// ---------------- top-20 per row, one wave per row (rows chunk-local) ----------------
__global__ __launch_bounds__(256) void k_topk(const float* __restrict__ D, int* __restrict__ idxo, int b0) {
    const int K = 20;
    int lane = threadIdx.x & 63;
    int rl = blockIdx.x * 4 + (threadIdx.x >> 6);
    const float* row = D + ((size_t)rl << 10);
    float d[16];
#pragma unroll
    for (int j = 0; j < 16; ++j) d[j] = row[lane + 64 * j];
    int rg = (b0 << 10) + rl;
    for (int it = 0; it < K; ++it) {
        float bv = d[0]; int bj = 0;
#pragma unroll
        for (int j = 1; j < 16; ++j) if (d[j] > bv) { bv = d[j]; bj = j; }
        int bm = lane + (bj << 6);
        for (int off = 32; off > 0; off >>= 1) {
            float ov = __shfl_down(bv, off);
            int   om = __shfl_down(bm, off);
            if (ov > bv || (ov == bv && om < bm)) { bv = ov; bm = om; }
        }
        bm = __shfl(bm, 0);
        if (lane == 0) idxo[rg * K + it] = bm;
        if ((bm & 63) == lane) d[bm >> 6] = -FLT_MAX;
    }
}

// ---- V[b][n][o] = X·Wa^T, U[b][n][o] = X·(Wb-Wa)^T ; c-major LDS, b128 frags ----
__global__ __launch_bounds__(256) void k_uv(const float* __restrict__ X, const float* __restrict__ w,
                                            float* __restrict__ V, float* __restrict__ U,
                                            int Cp, int C, int O) {
    int n0 = blockIdx.x * 64, o0 = blockIdx.y * 64, b = blockIdx.z;
    __shared__ float Xs[32 * 68], Was[32 * 68], Wds[32 * 68];
    int tid = threadIdx.x, ti = tid & 15, tj = tid >> 4;
    float accv[4][4] = {}, accu[4][4] = {};
    const float* Xb = X + (((size_t)b) << 10) * Cp;
    int W2 = 2 * C;
    for (int c0 = 0; c0 < Cp; c0 += 32) {
        for (int e = tid; e < 2048; e += 256) {
            int row = e >> 5, cc = e & 31, c = c0 + cc;
            Xs[cc * 68 + row] = (c < Cp) ? Xb[(size_t)(n0 + row) * Cp + c] : 0.f;
            float wa = 0.f, wd = 0.f;
            if (c < C) {
                float a_ = w[(size_t)(o0 + row) * W2 + c];
                float b_ = w[(size_t)(o0 + row) * W2 + C + c];
                wa = a_; wd = b_ - a_;
            }
            Was[cc * 68 + row] = wa; Wds[cc * 68 + row] = wd;
        }
        __syncthreads();
#pragma unroll 8
        for (int cc = 0; cc < 32; ++cc) {
            const float4 xv = *(const float4*)(Xs  + cc * 68 + 4 * tj);
            const float4 av = *(const float4*)(Was + cc * 68 + 4 * ti);
            const float4 dv = *(const float4*)(Wds + cc * 68 + 4 * ti);
            accv[0][0] += xv.x * av.x; accv[0][1] += xv.x * av.y; accv[0][2] += xv.x * av.z; accv[0][3] += xv.x * av.w;
            accv[1][0] += xv.y * av.x; accv[1][1] += xv.y * av.y; accv[1][2] += xv.y * av.z; accv[1][3] += xv.y * av.w;
            accv[2][0] += xv.z * av.x; accv[2][1] += xv.z * av.y; accv[2][2] += xv.z * av.z; accv[2][3] += xv.z * av.w;
            accv[3][0] += xv.w * av.x; accv[3][1] += xv.w * av.y; accv[3][2] += xv.w * av.z; accv[3][3] += xv.w * av.w;
            accu[0][0] += xv.x * dv.x; accu[0][1] += xv.x * dv.y; accu[0][2] += xv.x * dv.z; accu[0][3] += xv.x * dv.w;
            accu[1][0] += xv.y * dv.x; accu[1][1] += xv.y * dv.y; accu[1][2] += xv.y * dv.z; accu[1][3] += xv.y * dv.w;
            accu[2][0] += xv.z * dv.x; accu[2][1] += xv.z * dv.y; accu[2][2] += xv.z * dv.z; accu[2][3] += xv.z * dv.w;
            accu[3][0] += xv.w * dv.x; accu[3][1] += xv.w * dv.y; accu[3][2] += xv.w * dv.z; accu[3][3] += xv.w * dv.w;
        }
        __syncthreads();
    }
#pragma unroll
    for (int a = 0; a < 4; ++a) {
        int n = n0 + 4 * tj + a;
        size_t base = ((size_t)((b << 10) + n)) * O + o0 + 4 * ti;
        *(float4*)(V + base) = make_float4(accv[a][0], accv[a][1], accv[a][2], accv[a][3]);
        *(float4*)(U + base) = make_float4(accu[a][0], accu[a][1], accu[a][2], accu[a][3]);
    }
}

// ---- out[b][n][o] = max_k leaky(bn(V[m_k]+U[n])); writes f32 Xo, k-sliced bf16 HB, xx ----
__global__ __launch_bounds__(256) void k_gmax(const float* __restrict__ V, const float* __restrict__ U,
                                              const int* __restrict__ idx,
                                              const float* __restrict__ gg, const float* __restrict__ bb,
                                              float* __restrict__ Xo, float* __restrict__ xx,
                                              unsigned short* __restrict__ HB, int coff, int O) {
    __shared__ float sxx[4];
    int tid = threadIdx.x;
    int Tn = 256 / O;
    int j = tid / O, o = tid - j * O;
    int pt = blockIdx.x * Tn + j;          // global point = b*1024+n
    int b = pt >> 10, n = pt & 1023;
    float uv = U[(size_t)pt * O + o];
    float gv = gg[o], bv = bb[o];
    const int* ip = idx + (size_t)pt * 20;
    float mx = -FLT_MAX;
    for (int k = 0; k < 20; ++k) {
        int m = ip[k] & 1023;
        float vv = V[(size_t)((b << 10) + m) * O + o];
        float y = gv * ((vv + uv) * BNS_C) + bv;
        y = y > 0.f ? y : 0.2f * y;
        mx = fmaxf(mx, y);
    }
    Xo[(size_t)pt * O + o] = mx;
    int c = coff + o;
    HB[(((size_t)(b * 16 + (c >> 5)) << 10) + n) * 32 + (c & 31)] = f2bf(mx);
    float s = mx * mx;
#pragma unroll
    for (int off = 32; off; off >>= 1) s += __shfl_down(s, off);
    int wid = tid >> 6, lane = tid & 63;
    if (lane == 0) sxx[wid] = s;
    __syncthreads();
    if (o == 0) {
        int Wpp = O >> 6;
        float t = 0.f;
        for (int w = 0; w < Wpp; ++w) t += sxx[j * Wpp + w];
        xx[pt] = t;
    }
}

// ------- fused MFMA GEMM + BN/leaky + partial max/sum pool over a 256-row n-tile -------
__global__ __launch_bounds__(256) void k_final_mfma(const unsigned short* __restrict__ HB,
                                                    const float* __restrict__ w5,
                                                    const float* __restrict__ g5,
                                                    const float* __restrict__ b5,
                                                    float* __restrict__ pp) {
    int b = blockIdx.x;
    int nt = blockIdx.z;
    int wv = threadIdx.x >> 6, lane = threadIdx.x & 63;
    int r = lane & 15, q = lane >> 4;
    int o = blockIdx.y * 64 + wv * 16 + r;
    bf8 Bfr[16];
    const float* wrow = w5 + (size_t)o * 512 + q * 8;
#pragma unroll
    for (int s = 0; s < 16; ++s) {
        float4 f0 = *(const float4*)(wrow + s * 32);
        float4 f1 = *(const float4*)(wrow + s * 32 + 4);
        I4BF8 u_;
        u_.i.x = f2bf(f0.x) | ((unsigned)f2bf(f0.y) << 16);
        u_.i.y = f2bf(f0.z) | ((unsigned)f2bf(f0.w) << 16);
        u_.i.z = f2bf(f1.x) | ((unsigned)f2bf(f1.y) << 16);
        u_.i.w = f2bf(f1.z) | ((unsigned)f2bf(f1.w) << 16);
        Bfr[s] = u_.b;
    }
    float gb = g5[o] * BNS_C, bv = b5[o];
    float mx = -FLT_MAX, sm = 0.f;
    for (int g = 0; g < 4; ++g) {
        int row0 = (nt << 8) + (g << 6);
        f4 C0 = {0.f, 0.f, 0.f, 0.f}, C1 = C0, C2 = C0, C3 = C0;
#pragma unroll
        for (int s = 0; s < 16; ++s) {
            const unsigned short* slab = HB + (((size_t)(b * 16 + s) << 10) + row0) * 32 + q * 8;
            I4BF8 A0, A1, A2, A3;
            A0.i = *(const int4*)(slab + (size_t)( 0 + r) * 32);
            A1.i = *(const int4*)(slab + (size_t)(16 + r) * 32);
            A2.i = *(const int4*)(slab + (size_t)(32 + r) * 32);
            A3.i = *(const int4*)(slab + (size_t)(48 + r) * 32);
            C0 = __builtin_amdgcn_mfma_f32_16x16x32_bf16(A0.b, Bfr[s], C0, 0, 0, 0);
            C1 = __builtin_amdgcn_mfma_f32_16x16x32_bf16(A1.b, Bfr[s], C1, 0, 0, 0);
            C2 = __builtin_amdgcn_mfma_f32_16x16x32_bf16(A2.b, Bfr[s], C2, 0, 0, 0);
            C3 = __builtin_amdgcn_mfma_f32_16x16x32_bf16(A3.b, Bfr[s], C3, 0, 0, 0);
        }
#pragma unroll
        for (int e = 0; e < 4; ++e) {
            float y0 = gb * C0[e] + bv; y0 = y0 > 0.f ? y0 : 0.2f * y0; mx = fmaxf(mx, y0); sm += y0;
            float y1 = gb * C1[e] + bv; y1 = y1 > 0.f ? y1 : 0.2f * y1; mx = fmaxf(mx, y1); sm += y1;
            float y2 = gb * C2[e] + bv; y2 = y2 > 0.f ? y2 : 0.2f * y2; mx = fmaxf(mx, y2); sm += y2;
            float y3 = gb * C3[e] + bv; y3 = y3 > 0.f ? y3 : 0.2f * y3; mx = fmaxf(mx, y3); sm += y3;
        }
    }
    mx = fmaxf(mx, __shfl_down(mx, 32)); sm += __shfl_down(sm, 32);
    mx = fmaxf(mx, __shfl_down(mx, 16)); sm += __shfl_down(sm, 16);
    if (q == 0) {
        float* pb = pp + (size_t)(nt * 16 + b) * 2048;
        pb[o] = mx;
        pb[1024 + o] = sm;
    }
}

// ---- wl1 FC fused with the n-tile partial reduction: reads pp directly ----
__global__ __launch_bounds__(256) void k_fc2p(const float* __restrict__ pp, const float* __restrict__ w,
                                              const float* __restrict__ gg, const float* __restrict__ bb,
                                              float* __restrict__ out, int O) {
    int gw = blockIdx.x * 4 + (threadIdx.x >> 6);
    int lane = threadIdx.x & 63;
    int r = gw / O, o = gw - r * O;
    const float* wr = w + (size_t)o * 2048;
    float s = 0.f;
    for (int c = lane; c < 2048; c += 64) {
        const float* q0 = pp + (size_t)r * 2048 + c;
        float v;
        if (c < 1024) {
            v = fmaxf(fmaxf(q0[0], q0[16 * 2048]), fmaxf(q0[32 * 2048], q0[48 * 2048]));
        } else {
            v = (q0[0] + q0[16 * 2048] + q0[32 * 2048] + q0[48 * 2048]) * (1.f / 1024.f);
        }
        s += v * wr[c];
    }
#pragma unroll
    for (int off = 32; off; off >>= 1) s += __shfl_down(s, off);
    if (lane == 0) {
        float y = gg[o] * (s * BNS_C) + bb[o];
        out[gw] = y > 0.f ? y : 0.2f * y;
    }
}

// ------- FC tail mega-kernel -------
__global__ __launch_bounds__(256) void k_fc_tail(const float* __restrict__ z1,
                                                 const float* __restrict__ wl2, const float* __restrict__ g7, const float* __restrict__ b7,
                                                 const float* __restrict__ wl21,
                                                 const float* __restrict__ wl22, const float* __restrict__ g8, const float* __restrict__ b8,
                                                 const float* __restrict__ wl3,
                                                 float* __restrict__ out) {
    __shared__ float L0[4096];
    __shared__ float L1[2048];
    __shared__ float L2[1024];
    __shared__ float L3[512];
    int tid = threadIdx.x;
    for (int i = tid; i < 4096; i += 256) L0[i] = z1[i];
    __syncthreads();
    for (int idx = tid; idx < 2048; idx += 256) {
        int r = idx >> 7, o = idx & 127;
        const float* wr = wl2 + (size_t)o * 256;
        const float* ir = L0 + r * 256;
        float s = 0.f;
        for (int c = 0; c < 256; ++c) s += ir[c] * wr[c];
        float y = g7[o] * (s * BNS_C) + b7[o];
        L1[r * 128 + o] = y > 0.f ? y : 0.2f * y;
    }
    __syncthreads();
    for (int idx = tid; idx < 1024; idx += 256) {
        int r = idx >> 6, o = idx & 63;
        const float* wr = wl21 + (size_t)o * 128;
        const float* ir = L1 + r * 128;
        float s = 0.f;
        for (int c = 0; c < 128; ++c) s += ir[c] * wr[c];
        L2[r * 64 + o] = s;
    }
    __syncthreads();
    for (int idx = tid; idx < 512; idx += 256) {
        int r = idx >> 5, o = idx & 31;
        const float* wr = wl22 + (size_t)o * 64;
        const float* ir = L2 + r * 64;
        float s = 0.f;
        for (int c = 0; c < 64; ++c) s += ir[c] * wr[c];
        float y = g8[o] * (s * BNS_C) + b8[o];
        L3[r * 32 + o] = 0.5f * y * (1.f + erff(y * 0.70710678118654752f));
    }
    __syncthreads();
    for (int idx = tid; idx < 1440; idx += 256) {
        int r = idx / 90, o = idx - r * 90;
        const float* wr = wl3 + (size_t)o * 32;
        const float* ir = L3 + r * 32;
        float s = 0.f;
        for (int c = 0; c < 32; ++c) s += ir[c] * wr[c];
        out[r * 90 + o] = s;
    }
}

extern "C" void kernel_launch(void* const* d_in, const int* in_sizes, int n_in,
                              void* d_out, int out_size, void* d_ws, size_t ws_size,
                              hipStream_t stream) {
    typedef const float* fp;
    fp x  = (fp)d_in[0];
    fp w1 = (fp)d_in[2],  g1 = (fp)d_in[3],  b1 = (fp)d_in[4];
    fp w2 = (fp)d_in[5],  g2 = (fp)d_in[6],  b2 = (fp)d_in[7];
    fp w3 = (fp)d_in[8],  g3 = (fp)d_in[9],  b3 = (fp)d_in[10];
    fp w4 = (fp)d_in[11], g4 = (fp)d_in[12], b4 = (fp)d_in[13];
    fp w5 = (fp)d_in[14], g5 = (fp)d_in[15], b5 = (fp)d_in[16];
    fp wl1 = (fp)d_in[17], g6 = (fp)d_in[18], b6 = (fp)d_in[19];
    fp wl2 = (fp)d_in[20], g7 = (fp)d_in[21], b7 = (fp)d_in[22];
    fp wl21 = (fp)d_in[23], wl22 = (fp)d_in[24];
    fp g8 = (fp)d_in[25], b8 = (fp)d_in[26], wl3 = (fp)d_in[27];

    char* ws = (char*)d_ws;
    size_t off = 0;
    auto alloc = [&](size_t floats) { float* p_ = (float*)(ws + off); off += floats * 4; off = (off + 255) & ~(size_t)255; return p_; };
    float* X0  = alloc(131072);       // 16*1024*8
    float* X1  = alloc(1048576);      // [b][n][64]
    float* X2  = alloc(1048576);
    float* X3  = alloc(2097152);      // [b][n][128]
    float* X4  = alloc(4194304);      // [b][n][256]
    float* xx  = alloc(16384);
    int*   nbr = (int*)alloc(327680); // 16*1024*20
    unsigned short* HB = (unsigned short*)alloc(4194304);  // bf16 k-sliced [b][s][n][32]
    float* pp  = alloc(131072);       // 4 n-tile partials x 16 b x 2048
    float* z1  = alloc(4096);
    // pool: union of D | V+U
    size_t poolAvail = (ws_size > off) ? (ws_size - off) / 4 : 0;
    int fullD = poolAvail >= 16777216;                 // 64 MB full distance tensor
    float* pool = alloc(fullD ? 16777216 : 8388608);

    float* D = pool;
    float* V = pool;
    float* U = pool + 4194304;

    k_xin_t<<<64, 256, 0, stream>>>(x, X0, xx);

    struct Blk { const float* Xin; int Cp, C, O, coff; const float *w, *g, *b; float* Xout; };
    Blk blks[4] = {
        {X0, 8,   6,   64,  0,   w1, g1, b1, X1},
        {X1, 64,  64,  64,  64,  w2, g2, b2, X2},
        {X2, 64,  64,  128, 128, w3, g3, b3, X3},
        {X3, 128, 128, 256, 256, w4, g4, b4, X4},
    };
    for (int i = 0; i < 4; ++i) {
        const Blk& B_ = blks[i];
        if (fullD) {
            k_gram2<<<dim3(16, 16, 16), 256, 0, stream>>>(B_.Xin, xx, D, B_.Cp, 0);
            k_topk<<<4096, 256, 0, stream>>>(D, nbr, 0);
        } else {
            for (int b0 = 0; b0 < 16; b0 += 8) {
                k_gram2<<<dim3(16, 16, 8), 256, 0, stream>>>(B_.Xin, xx, D, B_.Cp, b0);
                k_topk<<<2048, 256, 0, stream>>>(D, nbr, b0);
            }
        }
        k_uv<<<dim3(16, B_.O / 64, 16), 256, 0, stream>>>(B_.Xin, B_.w, V, U, B_.Cp, B_.C, B_.O);
        int Tn = 256 / B_.O;
        k_gmax<<<16384 / Tn, 256, 0, stream>>>(V, U, nbr, B_.g, B_.b, B_.Xout, xx, HB, B_.coff, B_.O);
    }

    k_final_mfma<<<dim3(16, 16, 4), 256, 0, stream>>>(HB, w5, g5, b5, pp);

    k_fc2p<<<(16 * 256) / 4, 256, 0, stream>>>(pp, wl1, g6, b6, z1, 256);
    k_fc_tail<<<1, 256, 0, stream>>>(z1, wl2, g7, b7, wl21, wl22, g8, b8, wl3, (float*)d_out);
}

// Round 14
// 939.035 us; speedup vs baseline: 6.2474x; 1.0210x over previous
//
#include <hip/hip_runtime.h>
#include <math.h>
#include <float.h>

#define BNS_C 0.9999950000374996f /* 1/sqrt(1+1e-5) */

typedef __bf16 bf8 __attribute__((ext_vector_type(8)));
typedef float f4 __attribute__((ext_vector_type(4)));
union I4BF8 { int4 i; bf8 b; };

static __device__ __forceinline__ unsigned short f2bf(float f) {
    unsigned u = __float_as_uint(f);
    u += 0x7fff + ((u >> 16) & 1);          // round-to-nearest-even
    return (unsigned short)(u >> 16);
}

// ------- x[b][6][1024] -> X0[b][n][8] (zero-padded) + xx norms -------
__global__ void k_xin_t(const float* __restrict__ x, float* __restrict__ X0, float* __restrict__ xx) {
    int i = blockIdx.x * 256 + threadIdx.x;   // over 16384 points
    int b = i >> 10, n = i & 1023;
    const float* xb = x + (((size_t)b * 6) << 10) + n;
    float4* o4 = (float4*)(X0 + ((size_t)i << 3));
    float v0 = xb[0], v1 = xb[1 << 10], v2 = xb[2 << 10];
    float v3 = xb[3 << 10], v4 = xb[4 << 10], v5 = xb[5 << 10];
    o4[0] = make_float4(v0, v1, v2, v3);
    o4[1] = make_float4(v4, v5, 0.f, 0.f);
    xx[i] = v0*v0 + v1*v1 + v2*v2 + v3*v3 + v4*v4 + v5*v5;
}

// ---- D[z][n][m] = 2*X[n]·X[m] - xx[n] - xx[m]; c-major LDS, b128 frags ----
__global__ __launch_bounds__(256) void k_gram2(const float* __restrict__ X, const float* __restrict__ xx,
                                               float* __restrict__ D, int Cp, int b0) {
    int z = blockIdx.z, b = b0 + z;
    int n0 = blockIdx.y * 64, m0 = blockIdx.x * 64;
    __shared__ float As[32 * 68], Bs[32 * 68];   // [cc][row]
    int tid = threadIdx.x;
    int ti = tid & 15, tj = tid >> 4;
    float acc[4][4] = {};
    const float* Xb = X + (((size_t)b) << 10) * Cp;
    for (int c0 = 0; c0 < Cp; c0 += 32) {
        for (int e = tid; e < 2048; e += 256) {
            int row = e >> 5, cc = e & 31, c = c0 + cc;
            float a = 0.f, bb = 0.f;
            if (c < Cp) {
                a  = Xb[(size_t)(n0 + row) * Cp + c];
                bb = Xb[(size_t)(m0 + row) * Cp + c];
            }
            As[cc * 68 + row] = a; Bs[cc * 68 + row] = bb;
        }
        __syncthreads();
#pragma unroll 8
        for (int cc = 0; cc < 32; ++cc) {
            const float4 av = *(const float4*)(As + cc * 68 + 4 * tj);
            const float4 bv = *(const float4*)(Bs + cc * 68 + 4 * ti);
            acc[0][0] += av.x * bv.x; acc[0][1] += av.x * bv.y; acc[0][2] += av.x * bv.z; acc[0][3] += av.x * bv.w;
            acc[1][0] += av.y * bv.x; acc[1][1] += av.y * bv.y; acc[1][2] += av.y * bv.z; acc[1][3] += av.y * bv.w;
            acc[2][0] += av.z * bv.x; acc[2][1] += av.z * bv.y; acc[2][2] += av.z * bv.z; acc[2][3] += av.z * bv.w;
            acc[3][0] += av.w * bv.x; acc[3][1] += av.w * bv.y; acc[3][2] += av.w * bv.z; acc[3][3] += av.w * bv.w;
        }
        __syncthreads();
    }
    const float4 xm = *(const float4*)(xx + (b << 10) + m0 + 4 * ti);
#pragma unroll
    for (int a = 0; a < 4; ++a) {
        int n = n0 + 4 * tj + a;
        float xn = xx[(b << 10) + n];
        float4 o;
        o.x = 2.f * acc[a][0] - xn - xm.x;
        o.y = 2.f * acc[a][1] - xn - xm.y;
        o.z = 2.f * acc[a][2] - xn - xm.z;
        o.w = 2.f * acc[a][3] - xn - xm.w;
        *(float4*)(D + ((size_t)((z << 10) + n) << 10) + m0 + 4 * ti) = o;
    }
}

// ---------------- top-20 per row, one wave per row (rows chunk-local) ----------------
__global__ __launch_bounds__(256) void k_topk(const float* __restrict__ D, int* __restrict__ idxo, int b0) {
    const int K = 20;
    int lane = threadIdx.x & 63;
    int rl = blockIdx.x * 4 + (threadIdx.x >> 6);
    const float* row = D + ((size_t)rl << 10);
    float d[16];
#pragma unroll
    for (int j = 0; j < 16; ++j) d[j] = row[lane + 64 * j];
    int rg = (b0 << 10) + rl;
    for (int it = 0; it < K; ++it) {
        float bv = d[0]; int bj = 0;
#pragma unroll
        for (int j = 1; j < 16; ++j) if (d[j] > bv) { bv = d[j]; bj = j; }
        int bm = lane + (bj << 6);
        for (int off = 32; off > 0; off >>= 1) {
            float ov = __shfl_down(bv, off);
            int   om = __shfl_down(bm, off);
            if (ov > bv || (ov == bv && om < bm)) { bv = ov; bm = om; }
        }
        bm = __shfl(bm, 0);
        if (lane == 0) idxo[rg * K + it] = bm;
        if ((bm & 63) == lane) d[bm >> 6] = -FLT_MAX;
    }
}

// ---- V[b][n][o] = X·Wa^T, U[b][n][o] = X·(Wb-Wa)^T ; c-major LDS, b128 frags ----
__global__ __launch_bounds__(256) void k_uv(const float* __restrict__ X, const float* __restrict__ w,
                                            float* __restrict__ V, float* __restrict__ U,
                                            int Cp, int C, int O) {
    int n0 = blockIdx.x * 64, o0 = blockIdx.y * 64, b = blockIdx.z;
    __shared__ float Xs[32 * 68], Was[32 * 68], Wds[32 * 68];
    int tid = threadIdx.x, ti = tid & 15, tj = tid >> 4;
    float accv[4][4] = {}, accu[4][4] = {};
    const float* Xb = X + (((size_t)b) << 10) * Cp;
    int W2 = 2 * C;
    for (int c0 = 0; c0 < Cp; c0 += 32) {
        for (int e = tid; e < 2048; e += 256) {
            int row = e >> 5, cc = e & 31, c = c0 + cc;
            Xs[cc * 68 + row] = (c < Cp) ? Xb[(size_t)(n0 + row) * Cp + c] : 0.f;
            float wa = 0.f, wd = 0.f;
            if (c < C) {
                float a_ = w[(size_t)(o0 + row) * W2 + c];
                float b_ = w[(size_t)(o0 + row) * W2 + C + c];
                wa = a_; wd = b_ - a_;
            }
            Was[cc * 68 + row] = wa; Wds[cc * 68 + row] = wd;
        }
        __syncthreads();
#pragma unroll 8
        for (int cc = 0; cc < 32; ++cc) {
            const float4 xv = *(const float4*)(Xs  + cc * 68 + 4 * tj);
            const float4 av = *(const float4*)(Was + cc * 68 + 4 * ti);
            const float4 dv = *(const float4*)(Wds + cc * 68 + 4 * ti);
            accv[0][0] += xv.x * av.x; accv[0][1] += xv.x * av.y; accv[0][2] += xv.x * av.z; accv[0][3] += xv.x * av.w;
            accv[1][0] += xv.y * av.x; accv[1][1] += xv.y * av.y; accv[1][2] += xv.y * av.z; accv[1][3] += xv.y * av.w;
            accv[2][0] += xv.z * av.x; accv[2][1] += xv.z * av.y; accv[2][2] += xv.z * av.z; accv[2][3] += xv.z * av.w;
            accv[3][0] += xv.w * av.x; accv[3][1] += xv.w * av.y; accv[3][2] += xv.w * av.z; accv[3][3] += xv.w * av.w;
            accu[0][0] += xv.x * dv.x; accu[0][1] += xv.x * dv.y; accu[0][2] += xv.x * dv.z; accu[0][3] += xv.x * dv.w;
            accu[1][0] += xv.y * dv.x; accu[1][1] += xv.y * dv.y; accu[1][2] += xv.y * dv.z; accu[1][3] += xv.y * dv.w;
            accu[2][0] += xv.z * dv.x; accu[2][1] += xv.z * dv.y; accu[2][2] += xv.z * dv.z; accu[2][3] += xv.z * dv.w;
            accu[3][0] += xv.w * dv.x; accu[3][1] += xv.w * dv.y; accu[3][2] += xv.w * dv.z; accu[3][3] += xv.w * dv.w;
        }
        __syncthreads();
    }
#pragma unroll
    for (int a = 0; a < 4; ++a) {
        int n = n0 + 4 * tj + a;
        size_t base = ((size_t)((b << 10) + n)) * O + o0 + 4 * ti;
        *(float4*)(V + base) = make_float4(accv[a][0], accv[a][1], accv[a][2], accv[a][3]);
        *(float4*)(U + base) = make_float4(accu[a][0], accu[a][1], accu[a][2], accu[a][3]);
    }
}

// ---- out[b][n][o] = max_k leaky(bn(V[m_k]+U[n])); writes f32 Xo, k-sliced bf16 HB, xx ----
__global__ __launch_bounds__(256) void k_gmax(const float* __restrict__ V, const float* __restrict__ U,
                                              const int* __restrict__ idx,
                                              const float* __restrict__ gg, const float* __restrict__ bb,
                                              float* __restrict__ Xo, float* __restrict__ xx,
                                              unsigned short* __restrict__ HB, int coff, int O) {
    __shared__ float sxx[4];
    int tid = threadIdx.x;
    int Tn = 256 / O;
    int j = tid / O, o = tid - j * O;
    int pt = blockIdx.x * Tn + j;          // global point = b*1024+n
    int b = pt >> 10, n = pt & 1023;
    float uv = U[(size_t)pt * O + o];
    float gv = gg[o], bv = bb[o];
    const int* ip = idx + (size_t)pt * 20;
    float mx = -FLT_MAX;
    for (int k = 0; k < 20; ++k) {
        int m = ip[k] & 1023;
        float vv = V[(size_t)((b << 10) + m) * O + o];
        float y = gv * ((vv + uv) * BNS_C) + bv;
        y = y > 0.f ? y : 0.2f * y;
        mx = fmaxf(mx, y);
    }
    Xo[(size_t)pt * O + o] = mx;
    int c = coff + o;
    HB[(((size_t)(b * 16 + (c >> 5)) << 10) + n) * 32 + (c & 31)] = f2bf(mx);
    float s = mx * mx;
#pragma unroll
    for (int off = 32; off; off >>= 1) s += __shfl_down(s, off);
    int wid = tid >> 6, lane = tid & 63;
    if (lane == 0) sxx[wid] = s;
    __syncthreads();
    if (o == 0) {
        int Wpp = O >> 6;
        float t = 0.f;
        for (int w = 0; w < Wpp; ++w) t += sxx[j * Wpp + w];
        xx[pt] = t;
    }
}

// ------- fused MFMA GEMM + BN/leaky + partial max/sum pool over a 256-row n-tile -------
__global__ __launch_bounds__(256) void k_final_mfma(const unsigned short* __restrict__ HB,
                                                    const float* __restrict__ w5,
                                                    const float* __restrict__ g5,
                                                    const float* __restrict__ b5,
                                                    float* __restrict__ pp) {
    int b = blockIdx.x;
    int nt = blockIdx.z;
    int wv = threadIdx.x >> 6, lane = threadIdx.x & 63;
    int r = lane & 15, q = lane >> 4;
    int o = blockIdx.y * 64 + wv * 16 + r;
    bf8 Bfr[16];
    const float* wrow = w5 + (size_t)o * 512 + q * 8;
#pragma unroll
    for (int s = 0; s < 16; ++s) {
        float4 f0 = *(const float4*)(wrow + s * 32);
        float4 f1 = *(const float4*)(wrow + s * 32 + 4);
        I4BF8 u_;
        u_.i.x = f2bf(f0.x) | ((unsigned)f2bf(f0.y) << 16);
        u_.i.y = f2bf(f0.z) | ((unsigned)f2bf(f0.w) << 16);
        u_.i.z = f2bf(f1.x) | ((unsigned)f2bf(f1.y) << 16);
        u_.i.w = f2bf(f1.z) | ((unsigned)f2bf(f1.w) << 16);
        Bfr[s] = u_.b;
    }
    float gb = g5[o] * BNS_C, bv = b5[o];
    float mx = -FLT_MAX, sm = 0.f;
    for (int g = 0; g < 4; ++g) {
        int row0 = (nt << 8) + (g << 6);
        f4 C0 = {0.f, 0.f, 0.f, 0.f}, C1 = C0, C2 = C0, C3 = C0;
#pragma unroll
        for (int s = 0; s < 16; ++s) {
            const unsigned short* slab = HB + (((size_t)(b * 16 + s) << 10) + row0) * 32 + q * 8;
            I4BF8 A0, A1, A2, A3;
            A0.i = *(const int4*)(slab + (size_t)( 0 + r) * 32);
            A1.i = *(const int4*)(slab + (size_t)(16 + r) * 32);
            A2.i = *(const int4*)(slab + (size_t)(32 + r) * 32);
            A3.i = *(const int4*)(slab + (size_t)(48 + r) * 32);
            C0 = __builtin_amdgcn_mfma_f32_16x16x32_bf16(A0.b, Bfr[s], C0, 0, 0, 0);
            C1 = __builtin_amdgcn_mfma_f32_16x16x32_bf16(A1.b, Bfr[s], C1, 0, 0, 0);
            C2 = __builtin_amdgcn_mfma_f32_16x16x32_bf16(A2.b, Bfr[s], C2, 0, 0, 0);
            C3 = __builtin_amdgcn_mfma_f32_16x16x32_bf16(A3.b, Bfr[s], C3, 0, 0, 0);
        }
#pragma unroll
        for (int e = 0; e < 4; ++e) {
            float y0 = gb * C0[e] + bv; y0 = y0 > 0.f ? y0 : 0.2f * y0; mx = fmaxf(mx, y0); sm += y0;
            float y1 = gb * C1[e] + bv; y1 = y1 > 0.f ? y1 : 0.2f * y1; mx = fmaxf(mx, y1); sm += y1;
            float y2 = gb * C2[e] + bv; y2 = y2 > 0.f ? y2 : 0.2f * y2; mx = fmaxf(mx, y2); sm += y2;
            float y3 = gb * C3[e] + bv; y3 = y3 > 0.f ? y3 : 0.2f * y3; mx = fmaxf(mx, y3); sm += y3;
        }
    }
    mx = fmaxf(mx, __shfl_down(mx, 32)); sm += __shfl_down(sm, 32);
    mx = fmaxf(mx, __shfl_down(mx, 16)); sm += __shfl_down(sm, 16);
    if (q == 0) {
        float* pb = pp + (size_t)(nt * 16 + b) * 2048;
        pb[o] = mx;
        pb[1024 + o] = sm;
    }
}

// ---- wl1 FC fused with the n-tile partial reduction: reads pp directly ----
__global__ __launch_bounds__(256) void k_fc2p(const float* __restrict__ pp, const float* __restrict__ w,
                                              const float* __restrict__ gg, const float* __restrict__ bb,
                                              float* __restrict__ out, int O) {
    int gw = blockIdx.x * 4 + (threadIdx.x >> 6);
    int lane = threadIdx.x & 63;
    int r = gw / O, o = gw - r * O;
    const float* wr = w + (size_t)o * 2048;
    float s = 0.f;
    for (int c = lane; c < 2048; c += 64) {
        const float* q0 = pp + (size_t)r * 2048 + c;
        float v;
        if (c < 1024) {
            v = fmaxf(fmaxf(q0[0], q0[16 * 2048]), fmaxf(q0[32 * 2048], q0[48 * 2048]));
        } else {
            v = (q0[0] + q0[16 * 2048] + q0[32 * 2048] + q0[48 * 2048]) * (1.f / 1024.f);
        }
        s += v * wr[c];
    }
#pragma unroll
    for (int off = 32; off; off >>= 1) s += __shfl_down(s, off);
    if (lane == 0) {
        float y = gg[o] * (s * BNS_C) + bb[o];
        out[gw] = y > 0.f ? y : 0.2f * y;
    }
}

// ------- FC tail: one block per batch row, wave-per-output, coalesced weight loads -------
__global__ __launch_bounds__(256) void k_fc_tail(const float* __restrict__ z1,
                                                 const float* __restrict__ wl2, const float* __restrict__ g7, const float* __restrict__ b7,
                                                 const float* __restrict__ wl21,
                                                 const float* __restrict__ wl22, const float* __restrict__ g8, const float* __restrict__ b8,
                                                 const float* __restrict__ wl3,
                                                 float* __restrict__ out) {
    __shared__ float L1[128], L2[64], L3[32];
    int r = blockIdx.x;
    int tid = threadIdx.x, lane = tid & 63, wv = tid >> 6;
    // ---- layer A: 128 outs, C=256, bn7 + leaky; acts in registers ----
    const float* ir = z1 + r * 256;
    float a0 = ir[lane], a1 = ir[lane + 64], a2 = ir[lane + 128], a3 = ir[lane + 192];
    for (int ob = 0; ob < 32; ob += 2) {
        int o0 = wv * 32 + ob, o1 = o0 + 1;
        const float* w0 = wl2 + (size_t)o0 * 256;
        const float* w1 = wl2 + (size_t)o1 * 256;
        float s0 = a0 * w0[lane] + a1 * w0[lane + 64] + a2 * w0[lane + 128] + a3 * w0[lane + 192];
        float s1 = a0 * w1[lane] + a1 * w1[lane + 64] + a2 * w1[lane + 128] + a3 * w1[lane + 192];
#pragma unroll
        for (int off = 32; off; off >>= 1) { s0 += __shfl_down(s0, off); s1 += __shfl_down(s1, off); }
        if (lane == 0) {
            float y0 = g7[o0] * (s0 * BNS_C) + b7[o0]; L1[o0] = y0 > 0.f ? y0 : 0.2f * y0;
            float y1 = g7[o1] * (s1 * BNS_C) + b7[o1]; L1[o1] = y1 > 0.f ? y1 : 0.2f * y1;
        }
    }
    __syncthreads();
    // ---- layer B: 64 outs, C=128, linear ----
    float b0v = L1[lane], b1v = L1[lane + 64];
    for (int ob = 0; ob < 16; ob += 2) {
        int o0 = wv * 16 + ob, o1 = o0 + 1;
        const float* w0 = wl21 + (size_t)o0 * 128;
        const float* w1 = wl21 + (size_t)o1 * 128;
        float s0 = b0v * w0[lane] + b1v * w0[lane + 64];
        float s1 = b0v * w1[lane] + b1v * w1[lane + 64];
#pragma unroll
        for (int off = 32; off; off >>= 1) { s0 += __shfl_down(s0, off); s1 += __shfl_down(s1, off); }
        if (lane == 0) { L2[o0] = s0; L2[o1] = s1; }
    }
    __syncthreads();
    // ---- layer C: 32 outs, C=64, bn8 + exact gelu ----
    float c0v = L2[lane];
    for (int ob = 0; ob < 8; ob += 2) {
        int o0 = wv * 8 + ob, o1 = o0 + 1;
        float s0 = c0v * wl22[(size_t)o0 * 64 + lane];
        float s1 = c0v * wl22[(size_t)o1 * 64 + lane];
#pragma unroll
        for (int off = 32; off; off >>= 1) { s0 += __shfl_down(s0, off); s1 += __shfl_down(s1, off); }
        if (lane == 0) {
            float y0 = g8[o0] * (s0 * BNS_C) + b8[o0];
            L3[o0] = 0.5f * y0 * (1.f + erff(y0 * 0.70710678118654752f));
            float y1 = g8[o1] * (s1 * BNS_C) + b8[o1];
            L3[o1] = 0.5f * y1 * (1.f + erff(y1 * 0.70710678118654752f));
        }
    }
    __syncthreads();
    // ---- layer D: 90 outs, C=32, linear -> d_out ----
    float d0v = (lane < 32) ? L3[lane] : 0.f;
    for (int o = wv; o < 90; o += 4) {
        float s = (lane < 32) ? d0v * wl3[(size_t)o * 32 + lane] : 0.f;
#pragma unroll
        for (int off = 32; off; off >>= 1) s += __shfl_down(s, off);
        if (lane == 0) out[r * 90 + o] = s;
    }
}

extern "C" void kernel_launch(void* const* d_in, const int* in_sizes, int n_in,
                              void* d_out, int out_size, void* d_ws, size_t ws_size,
                              hipStream_t stream) {
    typedef const float* fp;
    fp x  = (fp)d_in[0];
    fp w1 = (fp)d_in[2],  g1 = (fp)d_in[3],  b1 = (fp)d_in[4];
    fp w2 = (fp)d_in[5],  g2 = (fp)d_in[6],  b2 = (fp)d_in[7];
    fp w3 = (fp)d_in[8],  g3 = (fp)d_in[9],  b3 = (fp)d_in[10];
    fp w4 = (fp)d_in[11], g4 = (fp)d_in[12], b4 = (fp)d_in[13];
    fp w5 = (fp)d_in[14], g5 = (fp)d_in[15], b5 = (fp)d_in[16];
    fp wl1 = (fp)d_in[17], g6 = (fp)d_in[18], b6 = (fp)d_in[19];
    fp wl2 = (fp)d_in[20], g7 = (fp)d_in[21], b7 = (fp)d_in[22];
    fp wl21 = (fp)d_in[23], wl22 = (fp)d_in[24];
    fp g8 = (fp)d_in[25], b8 = (fp)d_in[26], wl3 = (fp)d_in[27];

    char* ws = (char*)d_ws;
    size_t off = 0;
    auto alloc = [&](size_t floats) { float* p_ = (float*)(ws + off); off += floats * 4; off = (off + 255) & ~(size_t)255; return p_; };
    float* X0  = alloc(131072);       // 16*1024*8
    float* X1  = alloc(1048576);      // [b][n][64]
    float* X2  = alloc(1048576);
    float* X3  = alloc(2097152);      // [b][n][128]
    float* X4  = alloc(4194304);      // [b][n][256]
    float* xx  = alloc(16384);
    int*   nbr = (int*)alloc(327680); // 16*1024*20
    unsigned short* HB = (unsigned short*)alloc(4194304);  // bf16 k-sliced [b][s][n][32]
    float* pp  = alloc(131072);       // 4 n-tile partials x 16 b x 2048
    float* z1  = alloc(4096);
    // pool: union of D | V+U
    size_t poolAvail = (ws_size > off) ? (ws_size - off) / 4 : 0;
    int fullD = poolAvail >= 16777216;                 // 64 MB full distance tensor
    float* pool = alloc(fullD ? 16777216 : 8388608);

    float* D = pool;
    float* V = pool;
    float* U = pool + 4194304;

    k_xin_t<<<64, 256, 0, stream>>>(x, X0, xx);

    struct Blk { const float* Xin; int Cp, C, O, coff; const float *w, *g, *b; float* Xout; };
    Blk blks[4] = {
        {X0, 8,   6,   64,  0,   w1, g1, b1, X1},
        {X1, 64,  64,  64,  64,  w2, g2, b2, X2},
        {X2, 64,  64,  128, 128, w3, g3, b3, X3},
        {X3, 128, 128, 256, 256, w4, g4, b4, X4},
    };
    for (int i = 0; i < 4; ++i) {
        const Blk& B_ = blks[i];
        if (fullD) {
            k_gram2<<<dim3(16, 16, 16), 256, 0, stream>>>(B_.Xin, xx, D, B_.Cp, 0);
            k_topk<<<4096, 256, 0, stream>>>(D, nbr, 0);
        } else {
            for (int b0 = 0; b0 < 16; b0 += 8) {
                k_gram2<<<dim3(16, 16, 8), 256, 0, stream>>>(B_.Xin, xx, D, B_.Cp, b0);
                k_topk<<<2048, 256, 0, stream>>>(D, nbr, b0);
            }
        }
        k_uv<<<dim3(16, B_.O / 64, 16), 256, 0, stream>>>(B_.Xin, B_.w, V, U, B_.Cp, B_.C, B_.O);
        int Tn = 256 / B_.O;
        k_gmax<<<16384 / Tn, 256, 0, stream>>>(V, U, nbr, B_.g, B_.b, B_.Xout, xx, HB, B_.coff, B_.O);
    }

    k_final_mfma<<<dim3(16, 16, 4), 256, 0, stream>>>(HB, w5, g5, b5, pp);

    k_fc2p<<<(16 * 256) / 4, 256, 0, stream>>>(pp, wl1, g6, b6, z1, 256);
    k_fc_tail<<<16, 256, 0, stream>>>(z1, wl2, g7, b7, wl21, wl22, g8, b8, wl3, (float*)d_out);
}

// Round 15
// 832.845 us; speedup vs baseline: 7.0440x; 1.1275x over previous
//
#include <hip/hip_runtime.h>
#include <math.h>
#include <float.h>

#define BNS_C 0.9999950000374996f /* 1/sqrt(1+1e-5) */

typedef __bf16 bf8 __attribute__((ext_vector_type(8)));
typedef float f4 __attribute__((ext_vector_type(4)));
union I4BF8 { int4 i; bf8 b; };

static __device__ __forceinline__ unsigned short f2bf(float f) {
    unsigned u = __float_as_uint(f);
    u += 0x7fff + ((u >> 16) & 1);          // round-to-nearest-even
    return (unsigned short)(u >> 16);
}

// ------- x[b][6][1024] -> X0[b][n][8] (zero-padded) + xx norms -------
__global__ void k_xin_t(const float* __restrict__ x, float* __restrict__ X0, float* __restrict__ xx) {
    int i = blockIdx.x * 256 + threadIdx.x;   // over 16384 points
    int b = i >> 10, n = i & 1023;
    const float* xb = x + (((size_t)b * 6) << 10) + n;
    float4* o4 = (float4*)(X0 + ((size_t)i << 3));
    float v0 = xb[0], v1 = xb[1 << 10], v2 = xb[2 << 10];
    float v3 = xb[3 << 10], v4 = xb[4 << 10], v5 = xb[5 << 10];
    o4[0] = make_float4(v0, v1, v2, v3);
    o4[1] = make_float4(v4, v5, 0.f, 0.f);
    xx[i] = v0*v0 + v1*v1 + v2*v2 + v3*v3 + v4*v4 + v5*v5;
}

// ---- D[z][n][m] = 2*X[n]·X[m] - xx[n] - xx[m]; c-major LDS, b128 frags ----
__global__ __launch_bounds__(256) void k_gram2(const float* __restrict__ X, const float* __restrict__ xx,
                                               float* __restrict__ D, int Cp, int b0) {
    int z = blockIdx.z, b = b0 + z;
    int n0 = blockIdx.y * 64, m0 = blockIdx.x * 64;
    __shared__ float As[32 * 68], Bs[32 * 68];   // [cc][row]
    int tid = threadIdx.x;
    int ti = tid & 15, tj = tid >> 4;
    float acc[4][4] = {};
    const float* Xb = X + (((size_t)b) << 10) * Cp;
    for (int c0 = 0; c0 < Cp; c0 += 32) {
        for (int e = tid; e < 2048; e += 256) {
            int row = e >> 5, cc = e & 31, c = c0 + cc;
            float a = 0.f, bb = 0.f;
            if (c < Cp) {
                a  = Xb[(size_t)(n0 + row) * Cp + c];
                bb = Xb[(size_t)(m0 + row) * Cp + c];
            }
            As[cc * 68 + row] = a; Bs[cc * 68 + row] = bb;
        }
        __syncthreads();
#pragma unroll 8
        for (int cc = 0; cc < 32; ++cc) {
            const float4 av = *(const float4*)(As + cc * 68 + 4 * tj);
            const float4 bv = *(const float4*)(Bs + cc * 68 + 4 * ti);
            acc[0][0] += av.x * bv.x; acc[0][1] += av.x * bv.y; acc[0][2] += av.x * bv.z; acc[0][3] += av.x * bv.w;
            acc[1][0] += av.y * bv.x; acc[1][1] += av.y * bv.y; acc[1][2] += av.y * bv.z; acc[1][3] += av.y * bv.w;
            acc[2][0] += av.z * bv.x; acc[2][1] += av.z * bv.y; acc[2][2] += av.z * bv.z; acc[2][3] += av.z * bv.w;
            acc[3][0] += av.w * bv.x; acc[3][1] += av.w * bv.y; acc[3][2] += av.w * bv.z; acc[3][3] += av.w * bv.w;
        }
        __syncthreads();
    }
    const float4 xm = *(const float4*)(xx + (b << 10) + m0 + 4 * ti);
#pragma unroll
    for (int a = 0; a < 4; ++a) {
        int n = n0 + 4 * tj + a;
        float xn = xx[(b << 10) + n];
        float4 o;
        o.x = 2.f * acc[a][0] - xn - xm.x;
        o.y = 2.f * acc[a][1] - xn - xm.y;
        o.z = 2.f * acc[a][2] - xn - xm.z;
        o.w = 2.f * acc[a][3] - xn - xm.w;
        *(float4*)(D + ((size_t)((z << 10) + n) << 10) + m0 + 4 * ti) = o;
    }
}

// ---- top-20 per row: per-lane Batcher-sorted lists + u64 tournament ----
// key = (sortable(v) << 32) | (1023 - m): one u64 compare == (v desc, m asc). Exact.
#define CE(I,J) { if (kk[I] < kk[J]) { unsigned long long t_ = kk[I]; kk[I] = kk[J]; kk[J] = t_; } }
__global__ __launch_bounds__(256) void k_topk(const float* __restrict__ D, int* __restrict__ idxo, int b0) {
    __shared__ unsigned long long H[4096];       // [wv][16][64] = 32 KB
    int lane = threadIdx.x & 63, wv = threadIdx.x >> 6;
    int rl = blockIdx.x * 4 + wv;
    const float* row = D + ((size_t)rl << 10);
    unsigned long long kk[16];
#pragma unroll
    for (int j = 0; j < 16; ++j) {
        float v = row[lane + 64 * j];
        unsigned u = __float_as_uint(v);
        unsigned s = u ^ ((unsigned)(((int)u) >> 31) | 0x80000000u);
        int m = lane + (j << 6);
        kk[j] = ((unsigned long long)s << 32) | (unsigned)(1023 - m);
    }
    // Batcher odd-even mergesort, 16 inputs, descending (63 CEs)
    CE(0,1) CE(2,3) CE(0,2) CE(1,3) CE(1,2)
    CE(4,5) CE(6,7) CE(4,6) CE(5,7) CE(5,6)
    CE(0,4) CE(2,6) CE(2,4) CE(1,5) CE(3,7) CE(3,5) CE(1,2) CE(3,4) CE(5,6)
    CE(8,9) CE(10,11) CE(8,10) CE(9,11) CE(9,10)
    CE(12,13) CE(14,15) CE(12,14) CE(13,15) CE(13,14)
    CE(8,12) CE(10,14) CE(10,12) CE(9,13) CE(11,15) CE(11,13) CE(9,10) CE(11,12) CE(13,14)
    CE(0,8) CE(4,12) CE(4,8) CE(2,10) CE(6,14) CE(6,10) CE(2,4) CE(6,8) CE(10,12)
    CE(1,9) CE(5,13) CE(5,9) CE(3,11) CE(7,15) CE(7,11) CE(3,5) CE(7,9) CE(11,13)
    CE(1,2) CE(3,4) CE(5,6) CE(7,8) CE(9,10) CE(11,12) CE(13,14)
    // spill sorted list: bank depends only on lane -> conflict-free (2-way)
    unsigned long long* Hw = H + (wv << 10);
#pragma unroll
    for (int j = 0; j < 16; ++j) Hw[(j << 6) + lane] = kk[j];
    int ptr = 0;
    unsigned long long h = kk[0];
    int* outp = idxo + (size_t)((b0 << 10) + rl) * 20;
    for (int it = 0; it < 20; ++it) {
        unsigned long long bk = h;
#pragma unroll
        for (int off = 32; off; off >>= 1) {
            unsigned long long ok = __shfl_down(bk, off);
            if (ok > bk) bk = ok;
        }
        unsigned wlo = __builtin_amdgcn_readfirstlane((unsigned)bk);
        unsigned whi = __builtin_amdgcn_readfirstlane((unsigned)(bk >> 32));
        unsigned long long win = ((unsigned long long)whi << 32) | wlo;
        if (lane == 0) outp[it] = 1023 - (int)(wlo & 1023);
        if (h == win) {
            ++ptr;
            h = (ptr < 16) ? Hw[(ptr << 6) + lane] : 0ULL;
        }
    }
}
#undef CE

// ---- V[b][n][o] = X·Wa^T, U[b][n][o] = X·(Wb-Wa)^T ; c-major LDS, b128 frags ----
__global__ __launch_bounds__(256) void k_uv(const float* __restrict__ X, const float* __restrict__ w,
                                            float* __restrict__ V, float* __restrict__ U,
                                            int Cp, int C, int O) {
    int n0 = blockIdx.x * 64, o0 = blockIdx.y * 64, b = blockIdx.z;
    __shared__ float Xs[32 * 68], Was[32 * 68], Wds[32 * 68];
    int tid = threadIdx.x, ti = tid & 15, tj = tid >> 4;
    float accv[4][4] = {}, accu[4][4] = {};
    const float* Xb = X + (((size_t)b) << 10) * Cp;
    int W2 = 2 * C;
    for (int c0 = 0; c0 < Cp; c0 += 32) {
        for (int e = tid; e < 2048; e += 256) {
            int row = e >> 5, cc = e & 31, c = c0 + cc;
            Xs[cc * 68 + row] = (c < Cp) ? Xb[(size_t)(n0 + row) * Cp + c] : 0.f;
            float wa = 0.f, wd = 0.f;
            if (c < C) {
                float a_ = w[(size_t)(o0 + row) * W2 + c];
                float b_ = w[(size_t)(o0 + row) * W2 + C + c];
                wa = a_; wd = b_ - a_;
            }
            Was[cc * 68 + row] = wa; Wds[cc * 68 + row] = wd;
        }
        __syncthreads();
#pragma unroll 8
        for (int cc = 0; cc < 32; ++cc) {
            const float4 xv = *(const float4*)(Xs  + cc * 68 + 4 * tj);
            const float4 av = *(const float4*)(Was + cc * 68 + 4 * ti);
            const float4 dv = *(const float4*)(Wds + cc * 68 + 4 * ti);
            accv[0][0] += xv.x * av.x; accv[0][1] += xv.x * av.y; accv[0][2] += xv.x * av.z; accv[0][3] += xv.x * av.w;
            accv[1][0] += xv.y * av.x; accv[1][1] += xv.y * av.y; accv[1][2] += xv.y * av.z; accv[1][3] += xv.y * av.w;
            accv[2][0] += xv.z * av.x; accv[2][1] += xv.z * av.y; accv[2][2] += xv.z * av.z; accv[2][3] += xv.z * av.w;
            accv[3][0] += xv.w * av.x; accv[3][1] += xv.w * av.y; accv[3][2] += xv.w * av.z; accv[3][3] += xv.w * av.w;
            accu[0][0] += xv.x * dv.x; accu[0][1] += xv.x * dv.y; accu[0][2] += xv.x * dv.z; accu[0][3] += xv.x * dv.w;
            accu[1][0] += xv.y * dv.x; accu[1][1] += xv.y * dv.y; accu[1][2] += xv.y * dv.z; accu[1][3] += xv.y * dv.w;
            accu[2][0] += xv.z * dv.x; accu[2][1] += xv.z * dv.y; accu[2][2] += xv.z * dv.z; accu[2][3] += xv.z * dv.w;
            accu[3][0] += xv.w * dv.x; accu[3][1] += xv.w * dv.y; accu[3][2] += xv.w * dv.z; accu[3][3] += xv.w * dv.w;
        }
        __syncthreads();
    }
#pragma unroll
    for (int a = 0; a < 4; ++a) {
        int n = n0 + 4 * tj + a;
        size_t base = ((size_t)((b << 10) + n)) * O + o0 + 4 * ti;
        *(float4*)(V + base) = make_float4(accv[a][0], accv[a][1], accv[a][2], accv[a][3]);
        *(float4*)(U + base) = make_float4(accu[a][0], accu[a][1], accu[a][2], accu[a][3]);
    }
}

// ---- out[b][n][o] = max_k leaky(bn(V[m_k]+U[n])); writes f32 Xo, k-sliced bf16 HB, xx ----
__global__ __launch_bounds__(256) void k_gmax(const float* __restrict__ V, const float* __restrict__ U,
                                              const int* __restrict__ idx,
                                              const float* __restrict__ gg, const float* __restrict__ bb,
                                              float* __restrict__ Xo, float* __restrict__ xx,
                                              unsigned short* __restrict__ HB, int coff, int O) {
    __shared__ float sxx[4];
    int tid = threadIdx.x;
    int Tn = 256 / O;
    int j = tid / O, o = tid - j * O;
    int pt = blockIdx.x * Tn + j;          // global point = b*1024+n
    int b = pt >> 10, n = pt & 1023;
    float uv = U[(size_t)pt * O + o];
    float gv = gg[o], bv = bb[o];
    const int* ip = idx + (size_t)pt * 20;
    float mx = -FLT_MAX;
    for (int k = 0; k < 20; ++k) {
        int m = ip[k] & 1023;
        float vv = V[(size_t)((b << 10) + m) * O + o];
        float y = gv * ((vv + uv) * BNS_C) + bv;
        y = y > 0.f ? y : 0.2f * y;
        mx = fmaxf(mx, y);
    }
    Xo[(size_t)pt * O + o] = mx;
    int c = coff + o;
    HB[(((size_t)(b * 16 + (c >> 5)) << 10) + n) * 32 + (c & 31)] = f2bf(mx);
    float s = mx * mx;
#pragma unroll
    for (int off = 32; off; off >>= 1) s += __shfl_down(s, off);
    int wid = tid >> 6, lane = tid & 63;
    if (lane == 0) sxx[wid] = s;
    __syncthreads();
    if (o == 0) {
        int Wpp = O >> 6;
        float t = 0.f;
        for (int w = 0; w < Wpp; ++w) t += sxx[j * Wpp + w];
        xx[pt] = t;
    }
}

// ------- fused MFMA GEMM + BN/leaky + partial max/sum pool over a 256-row n-tile -------
__global__ __launch_bounds__(256) void k_final_mfma(const unsigned short* __restrict__ HB,
                                                    const float* __restrict__ w5,
                                                    const float* __restrict__ g5,
                                                    const float* __restrict__ b5,
                                                    float* __restrict__ pp) {
    int b = blockIdx.x;
    int nt = blockIdx.z;
    int wv = threadIdx.x >> 6, lane = threadIdx.x & 63;
    int r = lane & 15, q = lane >> 4;
    int o = blockIdx.y * 64 + wv * 16 + r;
    bf8 Bfr[16];
    const float* wrow = w5 + (size_t)o * 512 + q * 8;
#pragma unroll
    for (int s = 0; s < 16; ++s) {
        float4 f0 = *(const float4*)(wrow + s * 32);
        float4 f1 = *(const float4*)(wrow + s * 32 + 4);
        I4BF8 u_;
        u_.i.x = f2bf(f0.x) | ((unsigned)f2bf(f0.y) << 16);
        u_.i.y = f2bf(f0.z) | ((unsigned)f2bf(f0.w) << 16);
        u_.i.z = f2bf(f1.x) | ((unsigned)f2bf(f1.y) << 16);
        u_.i.w = f2bf(f1.z) | ((unsigned)f2bf(f1.w) << 16);
        Bfr[s] = u_.b;
    }
    float gb = g5[o] * BNS_C, bv = b5[o];
    float mx = -FLT_MAX, sm = 0.f;
    for (int g = 0; g < 4; ++g) {
        int row0 = (nt << 8) + (g << 6);
        f4 C0 = {0.f, 0.f, 0.f, 0.f}, C1 = C0, C2 = C0, C3 = C0;
#pragma unroll
        for (int s = 0; s < 16; ++s) {
            const unsigned short* slab = HB + (((size_t)(b * 16 + s) << 10) + row0) * 32 + q * 8;
            I4BF8 A0, A1, A2, A3;
            A0.i = *(const int4*)(slab + (size_t)( 0 + r) * 32);
            A1.i = *(const int4*)(slab + (size_t)(16 + r) * 32);
            A2.i = *(const int4*)(slab + (size_t)(32 + r) * 32);
            A3.i = *(const int4*)(slab + (size_t)(48 + r) * 32);
            C0 = __builtin_amdgcn_mfma_f32_16x16x32_bf16(A0.b, Bfr[s], C0, 0, 0, 0);
            C1 = __builtin_amdgcn_mfma_f32_16x16x32_bf16(A1.b, Bfr[s], C1, 0, 0, 0);
            C2 = __builtin_amdgcn_mfma_f32_16x16x32_bf16(A2.b, Bfr[s], C2, 0, 0, 0);
            C3 = __builtin_amdgcn_mfma_f32_16x16x32_bf16(A3.b, Bfr[s], C3, 0, 0, 0);
        }
#pragma unroll
        for (int e = 0; e < 4; ++e) {
            float y0 = gb * C0[e] + bv; y0 = y0 > 0.f ? y0 : 0.2f * y0; mx = fmaxf(mx, y0); sm += y0;
            float y1 = gb * C1[e] + bv; y1 = y1 > 0.f ? y1 : 0.2f * y1; mx = fmaxf(mx, y1); sm += y1;
            float y2 = gb * C2[e] + bv; y2 = y2 > 0.f ? y2 : 0.2f * y2; mx = fmaxf(mx, y2); sm += y2;
            float y3 = gb * C3[e] + bv; y3 = y3 > 0.f ? y3 : 0.2f * y3; mx = fmaxf(mx, y3); sm += y3;
        }
    }
    mx = fmaxf(mx, __shfl_down(mx, 32)); sm += __shfl_down(sm, 32);
    mx = fmaxf(mx, __shfl_down(mx, 16)); sm += __shfl_down(sm, 16);
    if (q == 0) {
        float* pb = pp + (size_t)(nt * 16 + b) * 2048;
        pb[o] = mx;
        pb[1024 + o] = sm;
    }
}

// ---- wl1 FC fused with the n-tile partial reduction: reads pp directly ----
__global__ __launch_bounds__(256) void k_fc2p(const float* __restrict__ pp, const float* __restrict__ w,
                                              const float* __restrict__ gg, const float* __restrict__ bb,
                                              float* __restrict__ out, int O) {
    int gw = blockIdx.x * 4 + (threadIdx.x >> 6);
    int lane = threadIdx.x & 63;
    int r = gw / O, o = gw - r * O;
    const float* wr = w + (size_t)o * 2048;
    float s = 0.f;
    for (int c = lane; c < 2048; c += 64) {
        const float* q0 = pp + (size_t)r * 2048 + c;
        float v;
        if (c < 1024) {
            v = fmaxf(fmaxf(q0[0], q0[16 * 2048]), fmaxf(q0[32 * 2048], q0[48 * 2048]));
        } else {
            v = (q0[0] + q0[16 * 2048] + q0[32 * 2048] + q0[48 * 2048]) * (1.f / 1024.f);
        }
        s += v * wr[c];
    }
#pragma unroll
    for (int off = 32; off; off >>= 1) s += __shfl_down(s, off);
    if (lane == 0) {
        float y = gg[o] * (s * BNS_C) + bb[o];
        out[gw] = y > 0.f ? y : 0.2f * y;
    }
}

// ------- FC tail: one block per batch row, wave-per-output, coalesced weight loads -------
__global__ __launch_bounds__(256) void k_fc_tail(const float* __restrict__ z1,
                                                 const float* __restrict__ wl2, const float* __restrict__ g7, const float* __restrict__ b7,
                                                 const float* __restrict__ wl21,
                                                 const float* __restrict__ wl22, const float* __restrict__ g8, const float* __restrict__ b8,
                                                 const float* __restrict__ wl3,
                                                 float* __restrict__ out) {
    __shared__ float L1[128], L2[64], L3[32];
    int r = blockIdx.x;
    int tid = threadIdx.x, lane = tid & 63, wv = tid >> 6;
    const float* ir = z1 + r * 256;
    float a0 = ir[lane], a1 = ir[lane + 64], a2 = ir[lane + 128], a3 = ir[lane + 192];
    for (int ob = 0; ob < 32; ob += 2) {
        int o0 = wv * 32 + ob, o1 = o0 + 1;
        const float* w0 = wl2 + (size_t)o0 * 256;
        const float* w1 = wl2 + (size_t)o1 * 256;
        float s0 = a0 * w0[lane] + a1 * w0[lane + 64] + a2 * w0[lane + 128] + a3 * w0[lane + 192];
        float s1 = a0 * w1[lane] + a1 * w1[lane + 64] + a2 * w1[lane + 128] + a3 * w1[lane + 192];
#pragma unroll
        for (int off = 32; off; off >>= 1) { s0 += __shfl_down(s0, off); s1 += __shfl_down(s1, off); }
        if (lane == 0) {
            float y0 = g7[o0] * (s0 * BNS_C) + b7[o0]; L1[o0] = y0 > 0.f ? y0 : 0.2f * y0;
            float y1 = g7[o1] * (s1 * BNS_C) + b7[o1]; L1[o1] = y1 > 0.f ? y1 : 0.2f * y1;
        }
    }
    __syncthreads();
    float b0v = L1[lane], b1v = L1[lane + 64];
    for (int ob = 0; ob < 16; ob += 2) {
        int o0 = wv * 16 + ob, o1 = o0 + 1;
        const float* w0 = wl21 + (size_t)o0 * 128;
        const float* w1 = wl21 + (size_t)o1 * 128;
        float s0 = b0v * w0[lane] + b1v * w0[lane + 64];
        float s1 = b0v * w1[lane] + b1v * w1[lane + 64];
#pragma unroll
        for (int off = 32; off; off >>= 1) { s0 += __shfl_down(s0, off); s1 += __shfl_down(s1, off); }
        if (lane == 0) { L2[o0] = s0; L2[o1] = s1; }
    }
    __syncthreads();
    float c0v = L2[lane];
    for (int ob = 0; ob < 8; ob += 2) {
        int o0 = wv * 8 + ob, o1 = o0 + 1;
        float s0 = c0v * wl22[(size_t)o0 * 64 + lane];
        float s1 = c0v * wl22[(size_t)o1 * 64 + lane];
#pragma unroll
        for (int off = 32; off; off >>= 1) { s0 += __shfl_down(s0, off); s1 += __shfl_down(s1, off); }
        if (lane == 0) {
            float y0 = g8[o0] * (s0 * BNS_C) + b8[o0];
            L3[o0] = 0.5f * y0 * (1.f + erff(y0 * 0.70710678118654752f));
            float y1 = g8[o1] * (s1 * BNS_C) + b8[o1];
            L3[o1] = 0.5f * y1 * (1.f + erff(y1 * 0.70710678118654752f));
        }
    }
    __syncthreads();
    float d0v = (lane < 32) ? L3[lane] : 0.f;
    for (int o = wv; o < 90; o += 4) {
        float s = (lane < 32) ? d0v * wl3[(size_t)o * 32 + lane] : 0.f;
#pragma unroll
        for (int off = 32; off; off >>= 1) s += __shfl_down(s, off);
        if (lane == 0) out[r * 90 + o] = s;
    }
}

extern "C" void kernel_launch(void* const* d_in, const int* in_sizes, int n_in,
                              void* d_out, int out_size, void* d_ws, size_t ws_size,
                              hipStream_t stream) {
    typedef const float* fp;
    fp x  = (fp)d_in[0];
    fp w1 = (fp)d_in[2],  g1 = (fp)d_in[3],  b1 = (fp)d_in[4];
    fp w2 = (fp)d_in[5],  g2 = (fp)d_in[6],  b2 = (fp)d_in[7];
    fp w3 = (fp)d_in[8],  g3 = (fp)d_in[9],  b3 = (fp)d_in[10];
    fp w4 = (fp)d_in[11], g4 = (fp)d_in[12], b4 = (fp)d_in[13];
    fp w5 = (fp)d_in[14], g5 = (fp)d_in[15], b5 = (fp)d_in[16];
    fp wl1 = (fp)d_in[17], g6 = (fp)d_in[18], b6 = (fp)d_in[19];
    fp wl2 = (fp)d_in[20], g7 = (fp)d_in[21], b7 = (fp)d_in[22];
    fp wl21 = (fp)d_in[23], wl22 = (fp)d_in[24];
    fp g8 = (fp)d_in[25], b8 = (fp)d_in[26], wl3 = (fp)d_in[27];

    char* ws = (char*)d_ws;
    size_t off = 0;
    auto alloc = [&](size_t floats) { float* p_ = (float*)(ws + off); off += floats * 4; off = (off + 255) & ~(size_t)255; return p_; };
    float* X0  = alloc(131072);       // 16*1024*8
    float* X1  = alloc(1048576);      // [b][n][64]
    float* X2  = alloc(1048576);
    float* X3  = alloc(2097152);      // [b][n][128]
    float* X4  = alloc(4194304);      // [b][n][256]
    float* xx  = alloc(16384);
    int*   nbr = (int*)alloc(327680); // 16*1024*20
    unsigned short* HB = (unsigned short*)alloc(4194304);  // bf16 k-sliced [b][s][n][32]
    float* pp  = alloc(131072);       // 4 n-tile partials x 16 b x 2048
    float* z1  = alloc(4096);
    // pool: union of D | V+U
    size_t poolAvail = (ws_size > off) ? (ws_size - off) / 4 : 0;
    int fullD = poolAvail >= 16777216;                 // 64 MB full distance tensor
    float* pool = alloc(fullD ? 16777216 : 8388608);

    float* D = pool;
    float* V = pool;
    float* U = pool + 4194304;

    k_xin_t<<<64, 256, 0, stream>>>(x, X0, xx);

    struct Blk { const float* Xin; int Cp, C, O, coff; const float *w, *g, *b; float* Xout; };
    Blk blks[4] = {
        {X0, 8,   6,   64,  0,   w1, g1, b1, X1},
        {X1, 64,  64,  64,  64,  w2, g2, b2, X2},
        {X2, 64,  64,  128, 128, w3, g3, b3, X3},
        {X3, 128, 128, 256, 256, w4, g4, b4, X4},
    };
    for (int i = 0; i < 4; ++i) {
        const Blk& B_ = blks[i];
        if (fullD) {
            k_gram2<<<dim3(16, 16, 16), 256, 0, stream>>>(B_.Xin, xx, D, B_.Cp, 0);
            k_topk<<<4096, 256, 0, stream>>>(D, nbr, 0);
        } else {
            for (int b0 = 0; b0 < 16; b0 += 8) {
                k_gram2<<<dim3(16, 16, 8), 256, 0, stream>>>(B_.Xin, xx, D, B_.Cp, b0);
                k_topk<<<2048, 256, 0, stream>>>(D, nbr, b0);
            }
        }
        k_uv<<<dim3(16, B_.O / 64, 16), 256, 0, stream>>>(B_.Xin, B_.w, V, U, B_.Cp, B_.C, B_.O);
        int Tn = 256 / B_.O;
        k_gmax<<<16384 / Tn, 256, 0, stream>>>(V, U, nbr, B_.g, B_.b, B_.Xout, xx, HB, B_.coff, B_.O);
    }

    k_final_mfma<<<dim3(16, 16, 4), 256, 0, stream>>>(HB, w5, g5, b5, pp);

    k_fc2p<<<(16 * 256) / 4, 256, 0, stream>>>(pp, wl1, g6, b6, z1, 256);
    k_fc_tail<<<16, 256, 0, stream>>>(z1, wl2, g7, b7, wl21, wl22, g8, b8, wl3, (float*)d_out);
}